// Round 12
// baseline (272.041 us; speedup 1.0000x reference)
//
#include <hip/hip_runtime.h>
#include <hip/hip_bf16.h>
#include <hip/hip_cooperative_groups.h>
#include <math.h>

namespace cg = cooperative_groups;

// Problem constants (FunctionNPairLoss): N=8192 rows, K=128 dims, 64 classes.
#define KD 128
#define NCLS 64
#define LOG2E 1.4426950408889634f
#define NEG2L -2.8853900817779268f
#define POS2L 2.8853900817779268f
#define LN2 0.6931471805599453f

typedef __attribute__((ext_vector_type(8))) short short8;
typedef __attribute__((ext_vector_type(4))) float f32x4;

struct SMZ { short8 A[2048]; short8 B[2048]; };                       // 64 KB (zmain)
struct SML { short8 M[4096]; float s2L[256]; float zfL[256]; int gidL[256]; float red[4]; };  // ~67 KB (loss)
struct SMS { int cnt[NCLS]; int off[NCLS]; int cur[NCLS]; };          // 768 B (scan)

__device__ inline void gload_lds16(const void* g, void* l) {
    __builtin_amdgcn_global_load_lds((const __attribute__((address_space(1))) unsigned int*)g,
                                     (__attribute__((address_space(3))) unsigned int*)l,
                                     16, 0, 0);
}
__device__ __forceinline__ float vexp2(float x) { float r; asm("v_exp_f32 %0, %1" : "=v"(r) : "v"(x)); return r; }
__device__ __forceinline__ float vlog2(float x) { float r; asm("v_log_f32 %0, %1" : "=v"(r) : "v"(x)); return r; }

// ================= phase 0a: cvt 16 rows + row norms + Z zero =================
__device__ __forceinline__ void dev_cvt(int b, int tid, const float* __restrict__ emb,
                                        short* __restrict__ embb, float* __restrict__ s2,
                                        float* __restrict__ Z) {
    const int r0 = b * 16;
    const size_t base = (size_t)r0 * KD;
    float4 a = *(const float4*)&emb[base + (size_t)tid * 8];
    float4 bb = *(const float4*)&emb[base + (size_t)tid * 8 + 4];
    short8 o;
    __hip_bfloat16 h;
    h = __float2bfloat16(a.x);  o[0] = *(short*)&h;
    h = __float2bfloat16(a.y);  o[1] = *(short*)&h;
    h = __float2bfloat16(a.z);  o[2] = *(short*)&h;
    h = __float2bfloat16(a.w);  o[3] = *(short*)&h;
    h = __float2bfloat16(bb.x); o[4] = *(short*)&h;
    h = __float2bfloat16(bb.y); o[5] = *(short*)&h;
    h = __float2bfloat16(bb.z); o[6] = *(short*)&h;
    h = __float2bfloat16(bb.w); o[7] = *(short*)&h;
    *(short8*)&embb[base + (size_t)tid * 8] = o;
    float s = a.x * a.x + a.y * a.y + a.z * a.z + a.w * a.w
            + bb.x * bb.x + bb.y * bb.y + bb.z * bb.z + bb.w * bb.w;
    s += __shfl_xor(s, 1, 64);
    s += __shfl_xor(s, 2, 64);
    s += __shfl_xor(s, 4, 64);
    s += __shfl_xor(s, 8, 64);
    if ((tid & 15) == 0) s2[r0 + (tid >> 4)] = s * LOG2E;
    if (tid < 16) Z[r0 + tid] = 0.f;
}

// ================= phase 0b (block 0): histogram -> scan -> scatter, zero lsum/ctr =================
__device__ __forceinline__ void dev_scan(int tid, const int* __restrict__ lab,
                                         int* __restrict__ cntG, int* __restrict__ offG,
                                         int* __restrict__ list, float* __restrict__ lsum,
                                         int* __restrict__ ctr, SMS* s, int N) {
    if (tid < NCLS) { s->cnt[tid] = 0; lsum[tid] = 0.f; }
    if (tid == 0) ctr[0] = 0;
    __syncthreads();
    for (int i = tid; i < N; i += 256) atomicAdd(&s->cnt[lab[i]], 1);
    __syncthreads();
    if (tid < NCLS) {
        int v = s->cnt[tid];
        int sc = v;
        for (int m = 1; m < 64; m <<= 1) {
            int t2 = __shfl_up(sc, m, 64);
            if (tid >= m) sc += t2;
        }
        s->off[tid] = sc - v;
        s->cur[tid] = 0;
        offG[tid] = sc - v;
        cntG[tid] = v;
    }
    __syncthreads();
    for (int i = tid; i < N; i += 256) {
        int c = lab[i];
        int p = atomicAdd(&s->cur[c], 1);
        list[s->off[c] + p] = i;
    }
}

// ================= phase 1: zmain (UNMASKED Zall, upper tile-triangle) =================
// Zall[i] = sum_{ALL j} 2^(s2i+s2j-2L*dot). Tile (it, jt=(it+d)&63), d in [0,31] (+32 for it<32).
__device__ void dev_zmain(int g, int it, int tid, const short* __restrict__ embb,
                          const float* __restrict__ s2, float* __restrict__ Z,
                          short8* A8, short8* B8) {
    const int w = tid >> 6, l = tid & 63;
    const int wr = w >> 1, wc = w & 1;
    const int i0 = it * 128;
    const short8* embv = (const short8*)embb;
    const int nd = 4 + ((g == 7 && it < 32) ? 1 : 0);

#pragma unroll
    for (int itr = 0; itr < 8; ++itr) {
        int lr = w * 32 + itr * 4 + (l >> 4);
        int c = (l & 15) ^ (lr & 7);
        gload_lds16(embv + (size_t)(i0 + lr) * 16 + c, &A8[w * 512 + itr * 64]);
    }
    {
        int j0 = ((it + g * 4) & 63) * 128;
#pragma unroll
        for (int itr = 0; itr < 8; ++itr) {
            int lr = w * 32 + itr * 4 + (l >> 4);
            int c = (l & 15) ^ (lr & 7);
            gload_lds16(embv + (size_t)(j0 + lr) * 16 + c, &B8[w * 512 + itr * 64]);
        }
    }

    float s2i[4][4];
#pragma unroll
    for (int mi = 0; mi < 4; ++mi)
#pragma unroll
        for (int r = 0; r < 4; ++r)
            s2i[mi][r] = s2[i0 + wr * 64 + mi * 16 + (l >> 4) * 4 + r];
    float zsum[4][4];
#pragma unroll
    for (int mi = 0; mi < 4; ++mi)
#pragma unroll
        for (int r = 0; r < 4; ++r) zsum[mi][r] = 0.f;

    __syncthreads();  // A and B0 staged

    short8 af[4][4];
#pragma unroll
    for (int mi = 0; mi < 4; ++mi) {
        int row = wr * 64 + mi * 16 + (l & 15);
        int rs = row * 16, rx = row & 7;
#pragma unroll
        for (int ks = 0; ks < 4; ++ks) {
            int kc = ks * 4 + (l >> 4);
            af[mi][ks] = A8[rs + (kc ^ rx)];
        }
    }
    __syncthreads();  // A8 free for B buffering

    for (int t = 0; t < nd; ++t) {
        const int d = (t < 4) ? (g * 4 + t) : 32;
        const int j0 = ((it + d) & 63) * 128;
        short8* rb = (t & 1) ? A8 : B8;
        short8* sb = (t & 1) ? B8 : A8;
        if (t + 1 < nd) {
            const int d1 = (t + 1 < 4) ? (g * 4 + t + 1) : 32;
            int j1 = ((it + d1) & 63) * 128;
#pragma unroll
            for (int itr = 0; itr < 8; ++itr) {
                int lr = w * 32 + itr * 4 + (l >> 4);
                int c = (l & 15) ^ (lr & 7);
                gload_lds16(embv + (size_t)(j1 + lr) * 16 + c, &sb[w * 512 + itr * 64]);
            }
        }

        f32x4 acc[4][4];
#pragma unroll
        for (int mi = 0; mi < 4; ++mi)
#pragma unroll
            for (int ni = 0; ni < 4; ++ni) acc[mi][ni] = (f32x4){0.f, 0.f, 0.f, 0.f};

#pragma unroll
        for (int ks = 0; ks < 4; ++ks) {
            short8 bf[4];
            int kc = ks * 4 + (l >> 4);
#pragma unroll
            for (int ni = 0; ni < 4; ++ni) {
                int row = wc * 64 + ni * 16 + (l & 15);
                bf[ni] = rb[row * 16 + (kc ^ (row & 7))];
            }
#pragma unroll
            for (int mi = 0; mi < 4; ++mi)
#pragma unroll
                for (int ni = 0; ni < 4; ++ni)
                    acc[mi][ni] = __builtin_amdgcn_mfma_f32_16x16x32_bf16(af[mi][ks], bf[ni], acc[mi][ni], 0, 0, 0);
        }

        float s2j[4];
#pragma unroll
        for (int ni = 0; ni < 4; ++ni)
            s2j[ni] = s2[j0 + wc * 64 + ni * 16 + (l & 15)];
        float cs[4] = {0.f, 0.f, 0.f, 0.f};
#pragma unroll
        for (int mi = 0; mi < 4; ++mi)
#pragma unroll
            for (int ni = 0; ni < 4; ++ni)
#pragma unroll
                for (int r = 0; r < 4; ++r) {
                    float e = vexp2(fmaf(NEG2L, acc[mi][ni][r], s2i[mi][r] + s2j[ni]));
                    zsum[mi][r] += e;
                    cs[ni] += e;
                }
        if (d > 0) {
#pragma unroll
            for (int ni = 0; ni < 4; ++ni) {
                float v = cs[ni];
                v += __shfl_xor(v, 16, 64);
                v += __shfl_xor(v, 32, 64);
                if ((l >> 4) == 0)
                    atomicAdd(&Z[j0 + wc * 64 + ni * 16 + (l & 15)], v);
            }
        }
        __syncthreads();
    }

#pragma unroll
    for (int mi = 0; mi < 4; ++mi)
#pragma unroll
        for (int r = 0; r < 4; ++r) {
            float v = zsum[mi][r];
            v += __shfl_xor(v, 1, 64);
            v += __shfl_xor(v, 2, 64);
            v += __shfl_xor(v, 4, 64);
            v += __shfl_xor(v, 8, 64);
            if ((l & 15) == 0)
                atomicAdd(&Z[i0 + wr * 64 + mi * 16 + (l >> 4) * 4 + r], v);
        }
}

// ================= Gram quadrant helper =================
__device__ __forceinline__ void gram_quad(const short8* M8, int l, int wr, int wc,
                                          int qi, int qj, f32x4 acc[4][4]) {
#pragma unroll
    for (int mi = 0; mi < 4; ++mi)
#pragma unroll
        for (int ni = 0; ni < 4; ++ni) acc[mi][ni] = (f32x4){0.f, 0.f, 0.f, 0.f};
#pragma unroll
    for (int ks = 0; ks < 4; ++ks) {
        short8 af[4], bf[4];
        int kc = ks * 4 + (l >> 4);
#pragma unroll
        for (int mi = 0; mi < 4; ++mi) {
            int row = qi * 128 + wr * 64 + mi * 16 + (l & 15);
            af[mi] = M8[row * 16 + (kc ^ (row & 7))];
        }
#pragma unroll
        for (int ni = 0; ni < 4; ++ni) {
            int row = qj * 128 + wc * 64 + ni * 16 + (l & 15);
            bf[ni] = M8[row * 16 + (kc ^ (row & 7))];
        }
#pragma unroll
        for (int mi = 0; mi < 4; ++mi)
#pragma unroll
            for (int ni = 0; ni < 4; ++ni)
                acc[mi][ni] = __builtin_amdgcn_mfma_f32_16x16x32_bf16(af[mi], bf[ni], acc[mi][ni], 0, 0, 0);
    }
}

// ================= phase 2: loss for (h, c); zsub aliased into zfL =================
__device__ void dev_loss(int h, int c, int tid, const short* __restrict__ embb,
                         const float* __restrict__ s2, const float* __restrict__ Z,
                         const int* __restrict__ cnt, const int* __restrict__ off,
                         const int* __restrict__ list, float* __restrict__ lsum,
                         SML* sm) {
    const int k = cnt[c], base = off[c];
    const int kp = min(k, 256);
    const int w = tid >> 6, l = tid & 63;
    const int wr = w >> 1, wc = w & 1;
    const short8* embv = (const short8*)embb;

    const bool active = (k >= 2) && !(h == 1 && kp <= 128);
    if (!active) return;

    {   // metadata; zfL doubles as zsub accumulator (zeroed here)
        int gg = list[base + min(tid, k - 1)];
        bool ok = tid < k;
        sm->s2L[tid] = ok ? s2[gg] : 0.f;
        sm->gidL[tid] = ok ? gg : 0x7fffffff;
        sm->zfL[tid] = 0.f;
    }
#pragma unroll
    for (int itr = 0; itr < 16; ++itr) {
        int grp = w * 16 + itr;
        if (grp * 4 >= kp) break;  // wave-uniform
        int lr = grp * 4 + (l >> 4);
        int ch = (l & 15) ^ (lr & 7);
        int gg = list[base + min(lr, k - 1)];
        gload_lds16(embv + (size_t)gg * 16 + ch, &sm->M[grp * 64]);
    }
    __syncthreads();

    const int two = (kp > 128);
    f32x4 acc[4][4];

    // ---- zsub pass (accumulates into zfL) ----
    for (int qq = 0; qq <= 2 * two; ++qq) {
        int qi = (qq == 2) ? 1 : 0;
        int qj = (qq == 0) ? 0 : 1;
        gram_quad(sm->M, l, wr, wc, qi, qj, acc);
        float rowsum[4][4];
#pragma unroll
        for (int mi = 0; mi < 4; ++mi)
#pragma unroll
            for (int r = 0; r < 4; ++r) rowsum[mi][r] = 0.f;
        float colsum[4] = {0.f, 0.f, 0.f, 0.f};
#pragma unroll
        for (int mi = 0; mi < 4; ++mi)
#pragma unroll
            for (int ni = 0; ni < 4; ++ni) {
                int pB = qi * 128 + wr * 64 + mi * 16 + (l >> 4) * 4;
                int qL = qj * 128 + wc * 64 + ni * 16 + (l & 15);
                float sj = sm->s2L[qL];
#pragma unroll
                for (int r = 0; r < 4; ++r) {
                    float e = vexp2(fmaf(NEG2L, acc[mi][ni][r], sm->s2L[pB + r] + sj));
                    e = ((pB + r) < k && qL < k) ? e : 0.f;
                    rowsum[mi][r] += e;
                    colsum[ni] += e;
                }
            }
#pragma unroll
        for (int mi = 0; mi < 4; ++mi)
#pragma unroll
            for (int r = 0; r < 4; ++r) {
                float v = rowsum[mi][r];
                v += __shfl_xor(v, 1, 64);
                v += __shfl_xor(v, 2, 64);
                v += __shfl_xor(v, 4, 64);
                v += __shfl_xor(v, 8, 64);
                if ((l & 15) == 0)
                    atomicAdd(&sm->zfL[qi * 128 + wr * 64 + mi * 16 + (l >> 4) * 4 + r], v);
            }
        if (qi != qj) {
#pragma unroll
            for (int ni = 0; ni < 4; ++ni) {
                float v = colsum[ni];
                v += __shfl_xor(v, 16, 64);
                v += __shfl_xor(v, 32, 64);
                if ((l >> 4) == 0)
                    atomicAdd(&sm->zfL[qj * 128 + wc * 64 + ni * 16 + (l & 15)], v);
            }
        }
    }
    __syncthreads();
    sm->zfL[tid] = (tid < k) ? (Z[sm->gidL[tid]] - sm->zfL[tid]) : 0.f;  // Zf in place
    __syncthreads();

    // ---- loss pass over own-half pairs ----
    float part = 0.f;
    int q0 = (h == 0) ? 0 : 2;
    int q1 = (h == 0) ? (two ? 1 : 0) : 2;
    for (int qq = q0; qq <= q1; ++qq) {
        int qi = (qq == 2) ? 1 : 0;
        int qj = (qq == 0) ? 0 : 1;
        gram_quad(sm->M, l, wr, wc, qi, qj, acc);
#pragma unroll
        for (int mi = 0; mi < 4; ++mi)
#pragma unroll
            for (int ni = 0; ni < 4; ++ni) {
                int qL = qj * 128 + wc * 64 + ni * 16 + (l & 15);
                float sj = sm->s2L[qL];
                float zq = sm->zfL[qL];
                int gb = sm->gidL[qL];
#pragma unroll
                for (int r = 0; r < 4; ++r) {
                    int pL = qi * 128 + wr * 64 + mi * 16 + (l >> 4) * 4 + r;
                    bool valid = (pL < qL) && (qL < k);
                    float arg = fmaf(POS2L, acc[mi][ni][r], -(sm->s2L[pL] + sj));
                    arg = valid ? arg : -160.f;
                    float e = vexp2(arg);
                    float z = (sm->gidL[pL] < gb) ? sm->zfL[pL] : zq;
                    part += vlog2(fmaf(z, e, 1.0f));
                }
            }
    }

    for (int m = 32; m; m >>= 1) part += __shfl_xor(part, m, 64);
    if (l == 0) sm->red[w] = part;
    __syncthreads();
    if (tid == 0)
        atomicAdd(&lsum[c], sm->red[0] + sm->red[1] + sm->red[2] + sm->red[3]);
}

// ================= finalize tail (last of 128 loss blocks) =================
__device__ __forceinline__ void dev_tail(int tid, float* __restrict__ lsum,
                                         int* __restrict__ cnt, int* __restrict__ ctr,
                                         float* __restrict__ out, int* lastB) {
    __threadfence();
    if (tid == 0) *lastB = (atomicAdd(ctr, 1) == 2 * NCLS - 1);
    __syncthreads();
    if (*lastB) {
        __threadfence();
        if (tid < 64) {
            int cc = tid;
            float ls = atomicAdd(&lsum[cc], 0.0f);
            int kk = atomicAdd(&cnt[cc], 0);
            float mean = 0.f;
            int valid = 0;
            long np = (long)kk * (kk - 1) / 2;
            if (np > 0) { mean = ls * LN2 / (float)np; valid = 1; }
            for (int m = 32; m; m >>= 1) {
                mean += __shfl_xor(mean, m, 64);
                valid += __shfl_xor(valid, m, 64);
            }
            if (cc == 0) out[0] = mean / (float)max(valid, 1);
        }
    }
}

// ================= fused cooperative kernel: 512 blocks, 3 phases =================
__global__ __launch_bounds__(256, 2) void fused_kernel(const float* __restrict__ emb,
                                                       const int* __restrict__ lab,
                                                       short* __restrict__ embb,
                                                       float* __restrict__ s2,
                                                       float* __restrict__ Z,
                                                       float* __restrict__ lsum,
                                                       int* __restrict__ cnt,
                                                       int* __restrict__ off,
                                                       int* __restrict__ list,
                                                       int* __restrict__ ctr,
                                                       float* __restrict__ out, int N) {
    __shared__ union { SMZ z; SML l; SMS s; } sm;
    __shared__ int lastB;
    const int tid = threadIdx.x;
    const int b = blockIdx.x;

    // phase 0: cvt all rows (512 blocks x 16); block 0 also scan/scatter + zero lsum/ctr
    dev_cvt(b, tid, emb, embb, s2, Z);
    if (b == 0) dev_scan(tid, lab, cnt, off, list, lsum, ctr, &sm.s, N);
    cg::this_grid().sync();

    // phase 1: zmain over the tile-triangle
    dev_zmain(b & 7, b >> 3, tid, embb, s2, Z, sm.z.A, sm.z.B);
    cg::this_grid().sync();

    // phase 2: loss on 128 blocks + finalize tail
    if (b < 2 * NCLS) {
        dev_loss(b & 1, b >> 1, tid, embb, s2, Z, cnt, off, list, lsum, &sm.l);
        dev_tail(tid, lsum, cnt, ctr, out, &lastB);
    }
}

// ================= fallback (non-cooperative) wrappers =================
__global__ __launch_bounds__(256) void prep_kernel(const float* __restrict__ emb,
                                                   const int* __restrict__ lab,
                                                   short* __restrict__ embb,
                                                   float* __restrict__ s2,
                                                   float* __restrict__ Z,
                                                   float* __restrict__ lsum,
                                                   int* __restrict__ cnt,
                                                   int* __restrict__ off,
                                                   int* __restrict__ list,
                                                   int* __restrict__ ctr, int N) {
    __shared__ SMS s;
    if (blockIdx.x == gridDim.x - 1)
        dev_scan(threadIdx.x, lab, cnt, off, list, lsum, ctr, &s, N);
    else
        dev_cvt(blockIdx.x, threadIdx.x, emb, embb, s2, Z);
}

__global__ __launch_bounds__(256, 2) void zmain_kernel(const short* __restrict__ embb,
                                                       const float* __restrict__ s2,
                                                       float* __restrict__ Z, int N) {
    __shared__ SMZ z;
    dev_zmain(blockIdx.x, blockIdx.y, threadIdx.x, embb, s2, Z, z.A, z.B);
}

__global__ __launch_bounds__(256, 2) void loss_kernel(const short* __restrict__ embb,
                                                      const float* __restrict__ s2,
                                                      const float* __restrict__ Z,
                                                      int* __restrict__ cnt,
                                                      const int* __restrict__ off,
                                                      const int* __restrict__ list,
                                                      float* __restrict__ lsum,
                                                      int* __restrict__ ctr,
                                                      float* __restrict__ out) {
    __shared__ SML sml;
    __shared__ int lastB;
    dev_loss(blockIdx.x, blockIdx.y, threadIdx.x, embb, s2, Z, cnt, off, list, lsum, &sml);
    dev_tail(threadIdx.x, lsum, cnt, ctr, out, &lastB);
}

extern "C" void kernel_launch(void* const* d_in, const int* in_sizes, int n_in,
                              void* d_out, int out_size, void* d_ws, size_t ws_size,
                              hipStream_t stream) {
    const float* emb = (const float*)d_in[0];
    const int* lab = (const int*)d_in[1];
    float* out = (float*)d_out;
    int N = in_sizes[1];  // 8192

    // workspace (4B units)
    float* ws = (float*)d_ws;
    float* Z = ws;                          // N (Zall)
    float* lsum = ws + N;                   // 64
    int* cnt = (int*)(ws + N + NCLS);       // 64
    int* off = cnt + NCLS;                  // 64
    int* ctr = off + NCLS;                  // 64 (1 used)
    int* list = ctr + NCLS;                 // N
    float* s2 = (float*)(list + N);         // N (||row||^2 * log2e)
    short* embb = (short*)(s2 + N);         // N*KD bf16 (2 MB), 16B-aligned

    void* args[] = {(void*)&emb, (void*)&lab, (void*)&embb, (void*)&s2, (void*)&Z,
                    (void*)&lsum, (void*)&cnt, (void*)&off, (void*)&list, (void*)&ctr,
                    (void*)&out, (void*)&N};
    hipError_t err = hipLaunchCooperativeKernel((const void*)fused_kernel,
                                                dim3(512), dim3(256), args, 0, stream);
    if (err != hipSuccess) {
        // fallback: proven 3-dispatch path
        prep_kernel<<<N / 16 + 1, 256, 0, stream>>>(emb, lab, embb, s2, Z, lsum, cnt, off, list, ctr, N);
        dim3 zgrid(8, N / 128);
        zmain_kernel<<<zgrid, 256, 0, stream>>>(embb, s2, Z, N);
        dim3 lgrid(2, NCLS);
        loss_kernel<<<lgrid, 256, 0, stream>>>(embb, s2, Z, cnt, off, list, lsum, ctr, out);
    }
}

// Round 13
// 115.652 us; speedup vs baseline: 2.3522x; 2.3522x over previous
//
#include <hip/hip_runtime.h>
#include <hip/hip_bf16.h>
#include <math.h>

// Problem constants (FunctionNPairLoss): N=8192 rows, K=128 dims, 64 classes.
#define KD 128
#define NCLS 64
#define LOG2E 1.4426950408889634f
#define NEG2L -2.8853900817779268f
#define POS2L 2.8853900817779268f
#define LN2 0.6931471805599453f

typedef __attribute__((ext_vector_type(8))) short short8;
typedef __attribute__((ext_vector_type(4))) float f32x4;

__device__ inline void gload_lds16(const void* g, void* l) {
    __builtin_amdgcn_global_load_lds((const __attribute__((address_space(1))) unsigned int*)g,
                                     (__attribute__((address_space(3))) unsigned int*)l,
                                     16, 0, 0);
}
__device__ __forceinline__ float vexp2(float x) { float r; asm("v_exp_f32 %0, %1" : "=v"(r) : "v"(x)); return r; }
__device__ __forceinline__ float vlog2(float x) { float r; asm("v_log_f32 %0, %1" : "=v"(r) : "v"(x)); return r; }

// ---------------- K0: scan+scatter, one 1024-thread block (window-resident) ----------------
// Also zeroes lsum + ctr (consumed by K3).
__global__ __launch_bounds__(1024) void scan_kernel(const int* __restrict__ lab,
                                                    int* __restrict__ cnt,
                                                    int* __restrict__ off,
                                                    int* __restrict__ list,
                                                    float* __restrict__ lsum,
                                                    int* __restrict__ ctr, int N) {
    __shared__ int cntL[NCLS], offL[NCLS], curL[NCLS];
    int tid = threadIdx.x;
    if (tid < NCLS) { cntL[tid] = 0; lsum[tid] = 0.f; }
    if (tid == 0) ctr[0] = 0;
    __syncthreads();
    for (int i = tid; i < N; i += 1024) atomicAdd(&cntL[lab[i]], 1);
    __syncthreads();
    if (tid < NCLS) {
        int v = cntL[tid];
        int s = v;
        for (int m = 1; m < 64; m <<= 1) {
            int t2 = __shfl_up(s, m, 64);
            if (tid >= m) s += t2;
        }
        offL[tid] = s - v;
        curL[tid] = 0;
        off[tid] = s - v;
        cnt[tid] = v;
    }
    __syncthreads();
    for (int i = tid; i < N; i += 1024) {
        int c = lab[i];
        int p = atomicAdd(&curL[c], 1);
        list[offL[c] + p] = i;
    }
}

// ---------------- K1: cvt 16 rows/block + row norms + Z zero (window-resident) ----------------
__global__ __launch_bounds__(256) void cvt_kernel(const float* __restrict__ emb,
                                                  short* __restrict__ embb,
                                                  float* __restrict__ s2,
                                                  float* __restrict__ Z, int N) {
    const int tid = threadIdx.x;
    const int r0 = blockIdx.x * 16;
    const size_t base = (size_t)r0 * KD;
    float4 a = *(const float4*)&emb[base + (size_t)tid * 8];
    float4 bb = *(const float4*)&emb[base + (size_t)tid * 8 + 4];
    short8 o;
    __hip_bfloat16 h;
    h = __float2bfloat16(a.x);  o[0] = *(short*)&h;
    h = __float2bfloat16(a.y);  o[1] = *(short*)&h;
    h = __float2bfloat16(a.z);  o[2] = *(short*)&h;
    h = __float2bfloat16(a.w);  o[3] = *(short*)&h;
    h = __float2bfloat16(bb.x); o[4] = *(short*)&h;
    h = __float2bfloat16(bb.y); o[5] = *(short*)&h;
    h = __float2bfloat16(bb.z); o[6] = *(short*)&h;
    h = __float2bfloat16(bb.w); o[7] = *(short*)&h;
    *(short8*)&embb[base + (size_t)tid * 8] = o;
    float s = a.x * a.x + a.y * a.y + a.z * a.z + a.w * a.w
            + bb.x * bb.x + bb.y * bb.y + bb.z * bb.z + bb.w * bb.w;
    s += __shfl_xor(s, 1, 64);
    s += __shfl_xor(s, 2, 64);
    s += __shfl_xor(s, 4, 64);
    s += __shfl_xor(s, 8, 64);
    if ((tid & 15) == 0) s2[r0 + (tid >> 4)] = s * LOG2E;
    if (tid < 16) Z[r0 + tid] = 0.f;
}

// ---------------- K2 zmain: UNMASKED Zall over the upper tile-triangle ----------------
// Zall[i] = sum_{ALL j} 2^(s2i+s2j-2L*dot). Tile (it, jt=(it+d)&63), d in [0,31] (+32 for it<32).
// Row sums always; col sums scattered when d>0. grid (8 d-groups, 64 i-tiles); 4 waves 2x2;
// A staged via swizzled global_load_lds -> regs; As8 reused as B dbuf slot 1.
__global__ __launch_bounds__(256, 2) void zmain_kernel(const short* __restrict__ embb,
                                                       const float* __restrict__ s2,
                                                       float* __restrict__ Z, int N) {
    __shared__ short8 As8[128 * 16];  // 32 KB: A stage, then B dbuf slot 1
    __shared__ short8 Bs8[128 * 16];  // 32 KB: B dbuf slot 0

    const int tid = threadIdx.x;
    const int w = tid >> 6, l = tid & 63;
    const int wr = w >> 1, wc = w & 1;
    const int g = blockIdx.x, it = blockIdx.y;
    const int i0 = it * 128;
    const short8* embv = (const short8*)embb;
    const int nd = 4 + ((g == 7 && it < 32) ? 1 : 0);

#pragma unroll
    for (int itr = 0; itr < 8; ++itr) {
        int lr = w * 32 + itr * 4 + (l >> 4);
        int c = (l & 15) ^ (lr & 7);
        gload_lds16(embv + (size_t)(i0 + lr) * 16 + c, &As8[w * 512 + itr * 64]);
    }
    {
        int j0 = ((it + g * 4) & 63) * 128;
#pragma unroll
        for (int itr = 0; itr < 8; ++itr) {
            int lr = w * 32 + itr * 4 + (l >> 4);
            int c = (l & 15) ^ (lr & 7);
            gload_lds16(embv + (size_t)(j0 + lr) * 16 + c, &Bs8[w * 512 + itr * 64]);
        }
    }

    float s2i[4][4];
#pragma unroll
    for (int mi = 0; mi < 4; ++mi)
#pragma unroll
        for (int r = 0; r < 4; ++r)
            s2i[mi][r] = s2[i0 + wr * 64 + mi * 16 + (l >> 4) * 4 + r];
    float zsum[4][4];
#pragma unroll
    for (int mi = 0; mi < 4; ++mi)
#pragma unroll
        for (int r = 0; r < 4; ++r) zsum[mi][r] = 0.f;

    __syncthreads();  // A and B0 staged

    short8 af[4][4];
#pragma unroll
    for (int mi = 0; mi < 4; ++mi) {
        int row = wr * 64 + mi * 16 + (l & 15);
        int rs = row * 16, rx = row & 7;
#pragma unroll
        for (int ks = 0; ks < 4; ++ks) {
            int kc = ks * 4 + (l >> 4);
            af[mi][ks] = As8[rs + (kc ^ rx)];
        }
    }
    __syncthreads();  // As8 free for B buffering

    for (int t = 0; t < nd; ++t) {
        const int d = (t < 4) ? (g * 4 + t) : 32;
        const int j0 = ((it + d) & 63) * 128;
        short8* rb = (t & 1) ? As8 : Bs8;
        short8* sb = (t & 1) ? Bs8 : As8;
        if (t + 1 < nd) {
            const int d1 = (t + 1 < 4) ? (g * 4 + t + 1) : 32;
            int j1 = ((it + d1) & 63) * 128;
#pragma unroll
            for (int itr = 0; itr < 8; ++itr) {
                int lr = w * 32 + itr * 4 + (l >> 4);
                int c = (l & 15) ^ (lr & 7);
                gload_lds16(embv + (size_t)(j1 + lr) * 16 + c, &sb[w * 512 + itr * 64]);
            }
        }

        f32x4 acc[4][4];
#pragma unroll
        for (int mi = 0; mi < 4; ++mi)
#pragma unroll
            for (int ni = 0; ni < 4; ++ni) acc[mi][ni] = (f32x4){0.f, 0.f, 0.f, 0.f};

#pragma unroll
        for (int ks = 0; ks < 4; ++ks) {
            short8 bf[4];
            int kc = ks * 4 + (l >> 4);
#pragma unroll
            for (int ni = 0; ni < 4; ++ni) {
                int row = wc * 64 + ni * 16 + (l & 15);
                bf[ni] = rb[row * 16 + (kc ^ (row & 7))];
            }
#pragma unroll
            for (int mi = 0; mi < 4; ++mi)
#pragma unroll
                for (int ni = 0; ni < 4; ++ni)
                    acc[mi][ni] = __builtin_amdgcn_mfma_f32_16x16x32_bf16(af[mi][ks], bf[ni], acc[mi][ni], 0, 0, 0);
        }

        float s2j[4];
#pragma unroll
        for (int ni = 0; ni < 4; ++ni)
            s2j[ni] = s2[j0 + wc * 64 + ni * 16 + (l & 15)];
        float cs[4] = {0.f, 0.f, 0.f, 0.f};
#pragma unroll
        for (int mi = 0; mi < 4; ++mi)
#pragma unroll
            for (int ni = 0; ni < 4; ++ni)
#pragma unroll
                for (int r = 0; r < 4; ++r) {
                    float e = vexp2(fmaf(NEG2L, acc[mi][ni][r], s2i[mi][r] + s2j[ni]));
                    zsum[mi][r] += e;
                    cs[ni] += e;
                }
        if (d > 0) {
#pragma unroll
            for (int ni = 0; ni < 4; ++ni) {
                float v = cs[ni];
                v += __shfl_xor(v, 16, 64);
                v += __shfl_xor(v, 32, 64);
                if ((l >> 4) == 0)
                    atomicAdd(&Z[j0 + wc * 64 + ni * 16 + (l & 15)], v);
            }
        }
        __syncthreads();
    }

#pragma unroll
    for (int mi = 0; mi < 4; ++mi)
#pragma unroll
        for (int r = 0; r < 4; ++r) {
            float v = zsum[mi][r];
            v += __shfl_xor(v, 1, 64);
            v += __shfl_xor(v, 2, 64);
            v += __shfl_xor(v, 4, 64);
            v += __shfl_xor(v, 8, 64);
            if ((l & 15) == 0)
                atomicAdd(&Z[i0 + wr * 64 + mi * 16 + (l >> 4) * 4 + r], v);
        }
}

// ---------------- Gram quadrant helper ----------------
__device__ __forceinline__ void gram_quad(const short8* Ms8, int l, int wr, int wc,
                                          int qi, int qj, f32x4 acc[4][4]) {
#pragma unroll
    for (int mi = 0; mi < 4; ++mi)
#pragma unroll
        for (int ni = 0; ni < 4; ++ni) acc[mi][ni] = (f32x4){0.f, 0.f, 0.f, 0.f};
#pragma unroll
    for (int ks = 0; ks < 4; ++ks) {
        short8 af[4], bf[4];
        int kc = ks * 4 + (l >> 4);
#pragma unroll
        for (int mi = 0; mi < 4; ++mi) {
            int row = qi * 128 + wr * 64 + mi * 16 + (l & 15);
            af[mi] = Ms8[row * 16 + (kc ^ (row & 7))];
        }
#pragma unroll
        for (int ni = 0; ni < 4; ++ni) {
            int row = qj * 128 + wc * 64 + ni * 16 + (l & 15);
            bf[ni] = Ms8[row * 16 + (kc ^ (row & 7))];
        }
#pragma unroll
        for (int mi = 0; mi < 4; ++mi)
#pragma unroll
            for (int ni = 0; ni < 4; ++ni)
                acc[mi][ni] = __builtin_amdgcn_mfma_f32_16x16x32_bf16(af[mi], bf[ni], acc[mi][ni], 0, 0, 0);
    }
}

// ---------------- K3: loss (grid (2,64)) + fused finalize tail ----------------
__global__ __launch_bounds__(256, 2) void loss_kernel(const short* __restrict__ embb,
                                                      const float* __restrict__ s2,
                                                      const float* __restrict__ Z,
                                                      int* __restrict__ cnt,
                                                      const int* __restrict__ off,
                                                      const int* __restrict__ list,
                                                      float* __restrict__ lsum,
                                                      int* __restrict__ ctr,
                                                      float* __restrict__ out) {
    __shared__ short8 Ms8[256 * 16];  // 64 KB staged rows
    __shared__ float s2L[256], zfL[256];
    __shared__ int gidL[256];
    __shared__ float red[4];
    __shared__ int lastB;

    const int h = blockIdx.x, c = blockIdx.y;
    const int k = cnt[c], base = off[c];
    const int kp = min(k, 256);
    const int tid = threadIdx.x;
    const int w = tid >> 6, l = tid & 63;
    const int wr = w >> 1, wc = w & 1;
    const short8* embv = (const short8*)embb;

    const bool active = (k >= 2) && !(h == 1 && kp <= 128);
    if (active) {
        {   // metadata; zfL doubles as zsub accumulator
            int gg = list[base + min(tid, k - 1)];
            bool ok = tid < k;
            s2L[tid] = ok ? s2[gg] : 0.f;
            gidL[tid] = ok ? gg : 0x7fffffff;
            zfL[tid] = 0.f;
        }
#pragma unroll
        for (int itr = 0; itr < 16; ++itr) {
            int grp = w * 16 + itr;
            if (grp * 4 >= kp) break;  // wave-uniform
            int lr = grp * 4 + (l >> 4);
            int ch = (l & 15) ^ (lr & 7);
            int gg = list[base + min(lr, k - 1)];
            gload_lds16(embv + (size_t)gg * 16 + ch, &Ms8[grp * 64]);
        }
        __syncthreads();

        const int two = (kp > 128);
        f32x4 acc[4][4];

        // ---- zsub pass (accumulates into zfL) ----
        for (int qq = 0; qq <= 2 * two; ++qq) {
            int qi = (qq == 2) ? 1 : 0;
            int qj = (qq == 0) ? 0 : 1;
            gram_quad(Ms8, l, wr, wc, qi, qj, acc);
            float rowsum[4][4];
#pragma unroll
            for (int mi = 0; mi < 4; ++mi)
#pragma unroll
                for (int r = 0; r < 4; ++r) rowsum[mi][r] = 0.f;
            float colsum[4] = {0.f, 0.f, 0.f, 0.f};
#pragma unroll
            for (int mi = 0; mi < 4; ++mi)
#pragma unroll
                for (int ni = 0; ni < 4; ++ni) {
                    int pB = qi * 128 + wr * 64 + mi * 16 + (l >> 4) * 4;
                    int qL = qj * 128 + wc * 64 + ni * 16 + (l & 15);
                    float sj = s2L[qL];
#pragma unroll
                    for (int r = 0; r < 4; ++r) {
                        float e = vexp2(fmaf(NEG2L, acc[mi][ni][r], s2L[pB + r] + sj));
                        e = ((pB + r) < k && qL < k) ? e : 0.f;
                        rowsum[mi][r] += e;
                        colsum[ni] += e;
                    }
                }
#pragma unroll
            for (int mi = 0; mi < 4; ++mi)
#pragma unroll
                for (int r = 0; r < 4; ++r) {
                    float v = rowsum[mi][r];
                    v += __shfl_xor(v, 1, 64);
                    v += __shfl_xor(v, 2, 64);
                    v += __shfl_xor(v, 4, 64);
                    v += __shfl_xor(v, 8, 64);
                    if ((l & 15) == 0)
                        atomicAdd(&zfL[qi * 128 + wr * 64 + mi * 16 + (l >> 4) * 4 + r], v);
                }
            if (qi != qj) {
#pragma unroll
                for (int ni = 0; ni < 4; ++ni) {
                    float v = colsum[ni];
                    v += __shfl_xor(v, 16, 64);
                    v += __shfl_xor(v, 32, 64);
                    if ((l >> 4) == 0)
                        atomicAdd(&zfL[qj * 128 + wc * 64 + ni * 16 + (l & 15)], v);
                }
            }
        }
        __syncthreads();
        zfL[tid] = (tid < k) ? (Z[gidL[tid]] - zfL[tid]) : 0.f;  // Zf in place
        __syncthreads();

        // ---- loss pass over own-half pairs ----
        float part = 0.f;
        int q0 = (h == 0) ? 0 : 2;
        int q1 = (h == 0) ? (two ? 1 : 0) : 2;
        for (int qq = q0; qq <= q1; ++qq) {
            int qi = (qq == 2) ? 1 : 0;
            int qj = (qq == 0) ? 0 : 1;
            gram_quad(Ms8, l, wr, wc, qi, qj, acc);
#pragma unroll
            for (int mi = 0; mi < 4; ++mi)
#pragma unroll
                for (int ni = 0; ni < 4; ++ni) {
                    int qL = qj * 128 + wc * 64 + ni * 16 + (l & 15);
                    float sj = s2L[qL];
                    float zq = zfL[qL];
                    int gb = gidL[qL];
#pragma unroll
                    for (int r = 0; r < 4; ++r) {
                        int pL = qi * 128 + wr * 64 + mi * 16 + (l >> 4) * 4 + r;
                        bool valid = (pL < qL) && (qL < k);
                        float arg = fmaf(POS2L, acc[mi][ni][r], -(s2L[pL] + sj));
                        arg = valid ? arg : -160.f;
                        float e = vexp2(arg);
                        float z = (gidL[pL] < gb) ? zfL[pL] : zq;
                        part += vlog2(fmaf(z, e, 1.0f));
                    }
                }
        }

        for (int m = 32; m; m >>= 1) part += __shfl_xor(part, m, 64);
        if (l == 0) red[w] = part;
        __syncthreads();
        if (tid == 0)
            atomicAdd(&lsum[c], red[0] + red[1] + red[2] + red[3]);
    }

    // ---- completion tail: last of the 128 blocks finalizes ----
    __threadfence();
    if (tid == 0) lastB = (atomicAdd(ctr, 1) == 2 * NCLS - 1);
    __syncthreads();
    if (lastB) {
        __threadfence();
        if (tid < 64) {
            int cc = tid;
            float ls = atomicAdd(&lsum[cc], 0.0f);
            int kk = atomicAdd(&cnt[cc], 0);
            float mean = 0.f;
            int valid = 0;
            long np = (long)kk * (kk - 1) / 2;
            if (np > 0) { mean = ls * LN2 / (float)np; valid = 1; }
            for (int m = 32; m; m >>= 1) {
                mean += __shfl_xor(mean, m, 64);
                valid += __shfl_xor(valid, m, 64);
            }
            if (cc == 0) out[0] = mean / (float)max(valid, 1);
        }
    }
}

extern "C" void kernel_launch(void* const* d_in, const int* in_sizes, int n_in,
                              void* d_out, int out_size, void* d_ws, size_t ws_size,
                              hipStream_t stream) {
    const float* emb = (const float*)d_in[0];
    const int* lab = (const int*)d_in[1];
    float* out = (float*)d_out;
    const int N = in_sizes[1];  // 8192

    // workspace (4B units)
    float* ws = (float*)d_ws;
    float* Z = ws;                          // N (Zall)
    float* lsum = ws + N;                   // 64
    int* cnt = (int*)(ws + N + NCLS);       // 64
    int* off = cnt + NCLS;                  // 64
    int* ctr = off + NCLS;                  // 64 (1 used)
    int* list = ctr + NCLS;                 // N
    float* s2 = (float*)(list + N);         // N (||row||^2 * log2e)
    short* embb = (short*)(s2 + N);         // N*KD bf16 (2 MB), 16B-aligned

    scan_kernel<<<1, 1024, 0, stream>>>(lab, cnt, off, list, lsum, ctr, N);
    cvt_kernel<<<N / 16, 256, 0, stream>>>(emb, embb, s2, Z, N);
    dim3 zgrid(8, N / 128);
    zmain_kernel<<<zgrid, 256, 0, stream>>>(embb, s2, Z, N);
    dim3 lgrid(2, NCLS);
    loss_kernel<<<lgrid, 256, 0, stream>>>(embb, s2, Z, cnt, off, list, lsum, ctr, out);
}